// Round 4
// baseline (346.083 us; speedup 1.0000x reference)
//
#include <hip/hip_runtime.h>
#include <stdint.h>

typedef unsigned long long u64;

#define N_ 128
#define C_ 256
#define H_ 28
#define W_ 28
#define HP_ (H_ / 2)
#define BN_EPS_ 1e-5f

// ---------------------------------------------------------------------------
// Kernel 1: bit-pack activations (unchanged; known-working).
// xbits layout: [n][h][w][4] u64; bit c&63 of word c>>6 = (x[n,c,h,w] < 0).
// ---------------------------------------------------------------------------
__global__ __launch_bounds__(256) void pack_x_kernel(const float* __restrict__ x,
                                                     u64* __restrict__ xbits) {
    int nh = blockIdx.x;            // n*H + h
    int h  = nh % H_;
    int n  = nh / H_;
    __shared__ float sx[C_][W_ + 1];   // 29696 B

    const float* xplane = x + ((size_t)n * C_ * H_ + h) * W_;  // + c*H*W + w
    for (int i = threadIdx.x; i < C_ * 7; i += 256) {
        int c = i / 7, q = i - c * 7;
        float4 v = *(const float4*)(xplane + (size_t)c * (H_ * W_) + q * 4);
        sx[c][q * 4 + 0] = v.x;
        sx[c][q * 4 + 1] = v.y;
        sx[c][q * 4 + 2] = v.z;
        sx[c][q * 4 + 3] = v.w;
    }
    __syncthreads();

    int k    = threadIdx.x >> 6;    // word index (wave id)
    int lane = threadIdx.x & 63;
    int c    = k * 64 + lane;
    u64 my = 0;
    #pragma unroll
    for (int w = 0; w < W_; ++w) {
        u64 mask = __ballot(sx[c][w] < 0.f);
        if (lane == w) my = mask;
    }
    if (lane < W_) xbits[((size_t)nh * W_ + lane) * 4 + k] = my;
}

// ---------------------------------------------------------------------------
// Kernel 2: bit-pack weights (unchanged). wbits layout: [co][tap(9)][4].
// tap = kh*3 + kw; bit ci&63 of word ci>>6 = (w[co,ci,kh,kw] < 0).
// ---------------------------------------------------------------------------
__global__ __launch_bounds__(256) void pack_w_kernel(const float* __restrict__ w,
                                                     u64* __restrict__ wbits) {
    int gid  = blockIdx.x * blockDim.x + threadIdx.x;
    int wave = gid >> 6;
    int lane = gid & 63;
    if (wave >= C_ * 9 * 4) return;
    int k    = wave & 3;
    int rest = wave >> 2;     // co*9 + tap
    int tap  = rest % 9;
    int co   = rest / 9;
    int ci   = k * 64 + lane;
    float val = w[((size_t)co * C_ + ci) * 9 + tap];
    u64 mask = __ballot(val < 0.f);
    if (lane == 0) wbits[wave] = mask;
}

// ---------------------------------------------------------------------------
// Kernel 3: binarized conv + BN + hardtanh + residual -- SGPR-weight design.
// Block = 128 threads (2 waves). Lane = spatial: ls = w + 28*h_sub (56/64
// active). Each wave serially covers 64 output channels; co is wave-uniform
// (readfirstlane), so the 9x4 u64 weight block loads via s_load into SGPRs
// and the inner loop is pure v_xor(v,s,v) + v_bcnt -- no vector-file weight
// state (rounds 1/3 showed the compiler mangles per-thread weight arrays).
// x bit-words (12 u64 = 24 VGPR) load once per block, reused across 64 cos.
// Per-lane tap-column sums A0/A1/A2 combine via 2 lane-shuffles:
//   out(w) = A0(w-1) + A1(w) + A2(w+1), edges masked via nvalid/corr.
// Zero-pad rows contribute popcount(ws) to the sums; corrected with scalar
// popcounts folded into integer bias B (edge blocks only, 2/14).
// ---------------------------------------------------------------------------
__global__ __launch_bounds__(128, 4) void conv_kernel(
    const u64* __restrict__ xbits, const u64* __restrict__ wbits,
    const float* __restrict__ x,
    const float* __restrict__ gamma, const float* __restrict__ beta,
    const float* __restrict__ mean, const float* __restrict__ var,
    float* __restrict__ out) {

    int bx = blockIdx.x;               // n*HP_ + hp
    int hp = bx % HP_;
    int n  = bx / HP_;
    int wv = __builtin_amdgcn_readfirstlane(threadIdx.x >> 6);   // 0..1, uniform
    int ls = threadIdx.x & 63;
    int co_base = (blockIdx.y * 2 + wv) * 64;

    bool active = ls < 56;
    int h_sub = (active && ls >= 28) ? 1 : 0;
    int w     = active ? (ls - h_sub * 28) : 0;
    int h     = hp * 2 + h_sub;

    // BN params for this wave's 64 cos: lane j holds co_base+j's inv/bias.
    float invV, biasV;
    {
        int cj = co_base + ls;
        float iv = gamma[cj] / sqrtf(var[cj] + BN_EPS_);
        invV  = iv;
        biasV = beta[cj] - mean[cj] * iv;
    }

    const bool wL = (w > 0), wR = (w < W_ - 1);
    int nrows  = 1 + (h > 0 ? 1 : 0) + (h < H_ - 1 ? 1 : 0);
    int ncols  = 1 + (wL ? 1 : 0) + (wR ? 1 : 0);
    int nvalid = C_ * nrows * ncols;

    // x bit-rows in registers: 3 rows x 4 words = 12 u64 (24 VGPR).
    u64 xr[3][4];
    #pragma unroll
    for (int r = 0; r < 3; ++r) {
        int ih = h - 1 + r;
        bool v = (ih >= 0) && (ih < H_);
        const ulonglong2* p = (const ulonglong2*)(
            xbits + (((size_t)n * H_ + (v ? ih : 0)) * W_ + w) * 4);
        ulonglong2 a, b;
        if (v) { a = p[0]; b = p[1]; }
        else   { a.x = a.y = b.x = b.y = 0ull; }
        xr[r][0] = a.x; xr[r][1] = a.y; xr[r][2] = b.x; xr[r][3] = b.y;
    }

    const bool edgeTop = (hp == 0);
    const bool edgeBot = (hp == HP_ - 1);

    size_t base = ((size_t)n * C_ + co_base) * (H_ * W_) + (size_t)h * W_ + w;
    const float* xp = x + base;
    float*       op = out + base;

    for (int j = 0; j < 64; ++j) {
        // Wave-uniform weight block: 9 taps x 4 u64 -> SGPRs via s_load.
        const u64* wsp = wbits + (size_t)(co_base + j) * 36;
        u64 ws[9][4];
        #pragma unroll
        for (int t = 0; t < 9; ++t) {
            #pragma unroll
            for (int k = 0; k < 4; ++k) ws[t][k] = wsp[t * 4 + k];
        }

        float res = *xp;   // residual, hoisted: latency hides under popcounts

        int A0 = 0, A1 = 0, A2 = 0;
        #pragma unroll
        for (int r = 0; r < 3; ++r) {
            #pragma unroll
            for (int k = 0; k < 4; ++k) {
                u64 xv = xr[r][k];
                A0 += (int)__popcll(xv ^ ws[r * 3 + 0][k]);
                A1 += (int)__popcll(xv ^ ws[r * 3 + 1][k]);
                A2 += (int)__popcll(xv ^ ws[r * 3 + 2][k]);
            }
        }
        int upA0 = __shfl_up(A0, 1);
        int dnA2 = __shfl_down(A2, 1);
        int S = A1 + (wL ? upA0 : 0) + (wR ? dnA2 : 0);

        int B = nvalid;
        if (edgeTop | edgeBot) {       // wave-uniform branch (2/14 blocks)
            int corr = 0;
            if (edgeTop && h == 0) {
                int P0 = (int)(__popcll(ws[0][0]) + __popcll(ws[0][1]) + __popcll(ws[0][2]) + __popcll(ws[0][3]));
                int P1 = (int)(__popcll(ws[1][0]) + __popcll(ws[1][1]) + __popcll(ws[1][2]) + __popcll(ws[1][3]));
                int P2 = (int)(__popcll(ws[2][0]) + __popcll(ws[2][1]) + __popcll(ws[2][2]) + __popcll(ws[2][3]));
                corr = P1 + (wL ? P0 : 0) + (wR ? P2 : 0);
            }
            if (edgeBot && h == H_ - 1) {
                int P6 = (int)(__popcll(ws[6][0]) + __popcll(ws[6][1]) + __popcll(ws[6][2]) + __popcll(ws[6][3]));
                int P7 = (int)(__popcll(ws[7][0]) + __popcll(ws[7][1]) + __popcll(ws[7][2]) + __popcll(ws[7][3]));
                int P8 = (int)(__popcll(ws[8][0]) + __popcll(ws[8][1]) + __popcll(ws[8][2]) + __popcll(ws[8][3]));
                corr = P7 + (wL ? P6 : 0) + (wR ? P8 : 0);
            }
            B += 2 * corr;
        }

        float inv  = __shfl(invV, j);
        float bias = __shfl(biasV, j);
        float val = (float)(B - 2 * S) * inv + bias;
        val = fminf(1.f, fmaxf(-1.f, val));
        if (active) *op = val + res;

        xp += H_ * W_;
        op += H_ * W_;
    }
}

// ---------------------------------------------------------------------------
extern "C" void kernel_launch(void* const* d_in, const int* in_sizes, int n_in,
                              void* d_out, int out_size, void* d_ws, size_t ws_size,
                              hipStream_t stream) {
    const float* x     = (const float*)d_in[0];
    const float* w     = (const float*)d_in[1];
    const float* gamma = (const float*)d_in[2];
    const float* beta  = (const float*)d_in[3];
    const float* mean  = (const float*)d_in[4];
    const float* var   = (const float*)d_in[5];
    float* out = (float*)d_out;

    u64* xbits = (u64*)d_ws;                                 // 128*28*28*4 u64 = 3.21 MB
    u64* wbits = xbits + (size_t)N_ * H_ * W_ * 4;           // 256*9*4 u64 = 72 KB

    pack_x_kernel<<<N_ * H_, 256, 0, stream>>>(x, xbits);
    pack_w_kernel<<<(C_ * 9 * 4 * 64) / 256, 256, 0, stream>>>(w, wbits);
    conv_kernel<<<dim3(N_ * HP_, 2), 128, 0, stream>>>(xbits, wbits, x, gamma, beta,
                                                       mean, var, out);
}